// Round 6
// baseline (119.064 us; speedup 1.0000x reference)
//
#include <hip/hip_runtime.h>
#include <hip/hip_cooperative_groups.h>

namespace cg = cooperative_groups;

// b=4, f=6, n_slots=7, n_buffer=8, h=w=128, 3 channels. bf=24.
constexpr int NB  = 8;
constexpr int NS  = 7;
constexpr int NCH = 3;
constexpr int HW  = 128 * 128;    // 16384
constexpr int HW4 = HW / 4;       // 4096 float4 per plane
constexpr int BF  = 24;
constexpr int BLOCK = 256;
constexpr int PXCHUNKS = HW / (BLOCK * 4);       // 16
constexpr int BLOCKS_PER_BF = PXCHUNKS * 2;      // 32 (x2 c-halves)
constexpr int NPART = BF * BLOCKS_PER_BF;        // 768 blocks / partials
constexpr float INV_HW = 1.0f / (float)HW;
constexpr float SCALE  = 20.0f / (4.0f * 6.0f * 7.0f * 8.0f);
constexpr float LOG_CLAMP = -100.0f;

// Computes this block's partial sum; valid on tid==0 only.
__device__ __forceinline__
float block_partial(const float* __restrict__ seg,
                    const float* __restrict__ masks,
                    const float* __restrict__ rec,
                    const float* __restrict__ rtgt,
                    const float* __restrict__ mvis,
                    const float* __restrict__ ai) {
    const int bid   = blockIdx.x;
    const int bf    = bid >> 5;                  // / BLOCKS_PER_BF
    const int rem   = bid & 31;
    const int half  = rem & 1;                   // c-half: 0 -> c=0..3, 1 -> c=4..7
    const int chunk = rem >> 1;                  // 0..15
    const int tid   = threadIdx.x;
    const int v4    = chunk * BLOCK + tid;       // float4 index in plane
    const int c0    = half * 4;

    __shared__ float ai_s[NS][NB];
    __shared__ float A_s[NB];
    if (tid < NS * NB)
        ((float*)ai_s)[tid] = ai[bf * NS * NB + tid];
    __syncthreads();
    if (tid < NB) {
        float a = 0.f;
        #pragma unroll
        for (int s = 0; s < NS; ++s) a += ai_s[s][tid];
        A_s[tid] = a;
    }
    __syncthreads();

    const float4* segp = (const float4*)(seg  + (size_t)bf * NB * HW)       + v4;
    const float4* mp   = (const float4*)(masks + (size_t)bf * NS * HW)      + v4;
    const float4* rp   = (const float4*)(rec  + (size_t)bf * NB * NCH * HW) + v4;
    const float4* tp   = (const float4*)(rtgt + (size_t)bf * NCH * HW)      + v4;
    const float4* vp   = (const float4*)(mvis + (size_t)bf * NS * HW)       + v4;

    // ---- Issue ALL 33 float4 loads up front; keep results live. ----
    float4 sv[4];
    #pragma unroll
    for (int c4 = 0; c4 < 4; ++c4) sv[c4] = segp[(c0 + c4) * HW4];

    float4 rr[4][NCH];
    #pragma unroll
    for (int c4 = 0; c4 < 4; ++c4)
        #pragma unroll
        for (int ch = 0; ch < NCH; ++ch)
            rr[c4][ch] = rp[((c0 + c4) * NCH + ch) * HW4];

    float4 mv[NS], vv[NS];
    #pragma unroll
    for (int s = 0; s < NS; ++s) mv[s] = mp[s * HW4];
    #pragma unroll
    for (int s = 0; s < NS; ++s) vv[s] = vp[s * HW4];

    float4 tv[NCH];
    #pragma unroll
    for (int ch = 0; ch < NCH; ++ch) tv[ch] = tp[ch * HW4];

    // ---- Compute ----
    float mb[NS][4], vb[NS][4];
    #pragma unroll
    for (int s = 0; s < NS; ++s) {
        const float* m4  = (const float*)&mv[s];
        const float* v4p = (const float*)&vv[s];
        #pragma unroll
        for (int j = 0; j < 4; ++j) {
            mb[s][j] = (m4[j]  > 0.5f) ? 1.f : 0.f;
            vb[s][j] = (v4p[j] > 0.5f) ? 1.f : 0.f;
        }
    }

    float acc = 0.f;
    #pragma unroll
    for (int c4 = 0; c4 < 4; ++c4) {
        const int c = c0 + c4;
        const float Ac = A_s[c];
        const float* sp  = (const float*)&sv[c4];
        const float* r0p = (const float*)&rr[c4][0];
        const float* r1p = (const float*)&rr[c4][1];
        const float* r2p = (const float*)&rr[c4][2];
        const float* t0p = (const float*)&tv[0];
        const float* t1p = (const float*)&tv[1];
        const float* t2p = (const float*)&tv[2];
        #pragma unroll
        for (int j = 0; j < 4; ++j) {
            float s  = sp[j];
            float lp = fmaxf(__logf(s), LOG_CLAMP);
            float l1 = fmaxf(__logf(1.0f - s), LOG_CLAMP);
            float d0 = r0p[j] - t0p[j];
            float d1 = r1p[j] - t1p[j];
            float d2 = r2p[j] - t2p[j];
            float D  = d0 * d0 + d1 * d1 + d2 * d2;
            float U = 0.f, V = 0.f;
            #pragma unroll
            for (int s7 = 0; s7 < NS; ++s7) {
                float a = ai_s[s7][c];
                U = fmaf(mb[s7][j], a, U);
                V = fmaf(vb[s7][j], a, V);
            }
            acc += -(Ac * l1 + U * (lp - l1)) * INV_HW + 0.1f * V * D;
        }
    }

    // wave reduce, cross-wave via LDS; result on tid 0
    #pragma unroll
    for (int off = 32; off; off >>= 1) acc += __shfl_down(acc, off, 64);
    __shared__ float wsum[BLOCK / 64];
    const int wid  = tid >> 6;
    const int lane = tid & 63;
    if (lane == 0) wsum[wid] = acc;
    __syncthreads();
    return wsum[0] + wsum[1] + wsum[2] + wsum[3];
}

// ---- Single-dispatch cooperative version ----
__global__ __launch_bounds__(BLOCK, 3)
void em_coop(const float* __restrict__ seg,  const float* __restrict__ masks,
             const float* __restrict__ rec,  const float* __restrict__ rtgt,
             const float* __restrict__ mvis, const float* __restrict__ ai,
             float* __restrict__ part, float* __restrict__ out) {
    float p = block_partial(seg, masks, rec, rtgt, mvis, ai);
    if (threadIdx.x == 0) part[blockIdx.x] = p;
    cg::this_grid().sync();
    if (blockIdx.x == 0) {
        const int tid = threadIdx.x;
        float a = part[tid] + part[tid + 256] + part[tid + 512];
        #pragma unroll
        for (int off = 32; off; off >>= 1) a += __shfl_down(a, off, 64);
        __shared__ float fsum[BLOCK / 64];
        if ((tid & 63) == 0) fsum[tid >> 6] = a;
        __syncthreads();
        if (tid == 0) out[0] = (fsum[0] + fsum[1] + fsum[2] + fsum[3]) * SCALE;
    }
}

// ---- Fallback: two-dispatch version (proven R5 path) ----
__global__ __launch_bounds__(BLOCK, 3)
void em_plain(const float* __restrict__ seg,  const float* __restrict__ masks,
              const float* __restrict__ rec,  const float* __restrict__ rtgt,
              const float* __restrict__ mvis, const float* __restrict__ ai,
              float* __restrict__ part) {
    float p = block_partial(seg, masks, rec, rtgt, mvis, ai);
    if (threadIdx.x == 0) part[blockIdx.x] = p;
}

__global__ __launch_bounds__(64)
void reduce_kernel(const float* __restrict__ part, float* __restrict__ out) {
    float a = 0.f;
    #pragma unroll
    for (int i = 0; i < NPART / 64; ++i)
        a += part[i * 64 + threadIdx.x];
    #pragma unroll
    for (int off = 32; off; off >>= 1) a += __shfl_down(a, off, 64);
    if (threadIdx.x == 0) out[0] = a * SCALE;
}

extern "C" void kernel_launch(void* const* d_in, const int* in_sizes, int n_in,
                              void* d_out, int out_size, void* d_ws, size_t ws_size,
                              hipStream_t stream) {
    const float* seg   = (const float*)d_in[0];  // (4,6,8,128,128)
    const float* masks = (const float*)d_in[1];  // (4,6,7,128,128)
    const float* rec   = (const float*)d_in[2];  // (4,6,8,3,128,128)
    const float* rtgt  = (const float*)d_in[3];  // (4,6,3,128,128)
    const float* mvis  = (const float*)d_in[4];  // (4,6,7,128,128)
    const float* ai    = (const float*)d_in[5];  // (4,6,7,8)
    float* out  = (float*)d_out;
    float* part = (float*)d_ws;                  // 768 floats, fully overwritten each call

    void* args[] = { (void*)&seg, (void*)&masks, (void*)&rec, (void*)&rtgt,
                     (void*)&mvis, (void*)&ai, (void*)&part, (void*)&out };
    hipError_t err = hipLaunchCooperativeKernel((const void*)em_coop,
                                                dim3(NPART), dim3(BLOCK),
                                                args, 0, stream);
    if (err != hipSuccess) {
        // Fallback: two-dispatch path (no atomics, no init needed).
        em_plain<<<NPART, BLOCK, 0, stream>>>(seg, masks, rec, rtgt, mvis, ai, part);
        reduce_kernel<<<1, 64, 0, stream>>>(part, out);
    }
}

// Round 7
// 44.464 us; speedup vs baseline: 2.6778x; 2.6778x over previous
//
#include <hip/hip_runtime.h>

// b=4, f=6, n_slots=7, n_buffer=8, h=w=128, 3 channels. bf=24.
constexpr int NB  = 8;
constexpr int NS  = 7;
constexpr int NCH = 3;
constexpr int HW  = 128 * 128;    // 16384
constexpr int HW4 = HW / 4;       // 4096 float4 per plane
constexpr int BF  = 24;
constexpr int BLOCK = 256;
constexpr int PXCHUNKS = HW / (BLOCK * 4);       // 16 px-chunks (1024 px each)
constexpr int CSPLIT = 4;                        // buffer dim split 4 ways (2 c's each)
constexpr int BLOCKS_PER_BF = PXCHUNKS * CSPLIT; // 64
constexpr int NPART = BF * BLOCKS_PER_BF;        // 1536 blocks / partials
constexpr float INV_HW = 1.0f / (float)HW;
constexpr float SCALE  = 20.0f / (4.0f * 6.0f * 7.0f * 8.0f);
constexpr float LOG_CLAMP = -100.0f;

__global__ __launch_bounds__(BLOCK, 6)   // cap VGPR ~85 -> 6 blocks/CU with this grid
void em_loss_kernel(const float* __restrict__ seg,
                    const float* __restrict__ masks,
                    const float* __restrict__ rec,
                    const float* __restrict__ rtgt,
                    const float* __restrict__ mvis,
                    const float* __restrict__ ai,
                    float* __restrict__ part) {
    const int bid    = blockIdx.x;
    const int bf     = bid >> 6;                 // / BLOCKS_PER_BF
    const int rem    = bid & 63;
    const int csplit = rem & 3;                  // 0..3 -> c = 2*csplit, 2*csplit+1
    const int chunk  = rem >> 2;                 // 0..15
    const int tid    = threadIdx.x;
    const int v4     = chunk * BLOCK + tid;      // float4 index in plane
    const int c0     = csplit * 2;

    __shared__ float ai_s[NS][NB];
    __shared__ float A_s[NB];
    if (tid < NS * NB)
        ((float*)ai_s)[tid] = ai[bf * NS * NB + tid];
    __syncthreads();
    if (tid < NB) {
        float a = 0.f;
        #pragma unroll
        for (int s = 0; s < NS; ++s) a += ai_s[s][tid];
        A_s[tid] = a;
    }
    __syncthreads();

    const float4* segp = (const float4*)(seg  + (size_t)bf * NB * HW)       + v4;
    const float4* mp   = (const float4*)(masks + (size_t)bf * NS * HW)      + v4;
    const float4* rp   = (const float4*)(rec  + (size_t)bf * NB * NCH * HW) + v4;
    const float4* tp   = (const float4*)(rtgt + (size_t)bf * NCH * HW)      + v4;
    const float4* vp   = (const float4*)(mvis + (size_t)bf * NS * HW)       + v4;

    // ---- 25 float4 loads: 2 seg + 6 rec + 7 masks + 7 mvis + 3 rtgt ----
    float4 sv[2];
    #pragma unroll
    for (int c4 = 0; c4 < 2; ++c4) sv[c4] = segp[(c0 + c4) * HW4];

    float4 rr[2][NCH];
    #pragma unroll
    for (int c4 = 0; c4 < 2; ++c4)
        #pragma unroll
        for (int ch = 0; ch < NCH; ++ch)
            rr[c4][ch] = rp[((c0 + c4) * NCH + ch) * HW4];

    float4 mv[NS], vv[NS];
    #pragma unroll
    for (int s = 0; s < NS; ++s) mv[s] = mp[s * HW4];
    #pragma unroll
    for (int s = 0; s < NS; ++s) vv[s] = vp[s * HW4];

    float4 tv[NCH];
    #pragma unroll
    for (int ch = 0; ch < NCH; ++ch) tv[ch] = tp[ch * HW4];

    // ---- Compute ----
    float mb[NS][4], vb[NS][4];
    #pragma unroll
    for (int s = 0; s < NS; ++s) {
        const float* m4  = (const float*)&mv[s];
        const float* v4p = (const float*)&vv[s];
        #pragma unroll
        for (int j = 0; j < 4; ++j) {
            mb[s][j] = (m4[j]  > 0.5f) ? 1.f : 0.f;
            vb[s][j] = (v4p[j] > 0.5f) ? 1.f : 0.f;
        }
    }

    float acc = 0.f;
    #pragma unroll
    for (int c4 = 0; c4 < 2; ++c4) {
        const int c = c0 + c4;
        const float Ac = A_s[c];
        const float* sp  = (const float*)&sv[c4];
        const float* r0p = (const float*)&rr[c4][0];
        const float* r1p = (const float*)&rr[c4][1];
        const float* r2p = (const float*)&rr[c4][2];
        const float* t0p = (const float*)&tv[0];
        const float* t1p = (const float*)&tv[1];
        const float* t2p = (const float*)&tv[2];
        #pragma unroll
        for (int j = 0; j < 4; ++j) {
            float s  = sp[j];
            float lp = fmaxf(__logf(s), LOG_CLAMP);
            float l1 = fmaxf(__logf(1.0f - s), LOG_CLAMP);
            float d0 = r0p[j] - t0p[j];
            float d1 = r1p[j] - t1p[j];
            float d2 = r2p[j] - t2p[j];
            float D  = d0 * d0 + d1 * d1 + d2 * d2;
            float U = 0.f, V = 0.f;
            #pragma unroll
            for (int s7 = 0; s7 < NS; ++s7) {
                float a = ai_s[s7][c];
                U = fmaf(mb[s7][j], a, U);
                V = fmaf(vb[s7][j], a, V);
            }
            acc += -(Ac * l1 + U * (lp - l1)) * INV_HW + 0.1f * V * D;
        }
    }

    // wave reduce, cross-wave via LDS, one plain store per block (no atomics)
    #pragma unroll
    for (int off = 32; off; off >>= 1) acc += __shfl_down(acc, off, 64);
    __shared__ float wsum[BLOCK / 64];
    const int wid  = tid >> 6;
    const int lane = tid & 63;
    if (lane == 0) wsum[wid] = acc;
    __syncthreads();
    if (tid == 0)
        part[blockIdx.x] = wsum[0] + wsum[1] + wsum[2] + wsum[3];
}

__global__ __launch_bounds__(BLOCK)
void reduce_kernel(const float* __restrict__ part, float* __restrict__ out) {
    const int tid = threadIdx.x;
    float a = 0.f;
    #pragma unroll
    for (int i = 0; i < NPART / BLOCK; ++i)      // 6 each
        a += part[i * BLOCK + tid];
    #pragma unroll
    for (int off = 32; off; off >>= 1) a += __shfl_down(a, off, 64);
    __shared__ float fsum[BLOCK / 64];
    if ((tid & 63) == 0) fsum[tid >> 6] = a;
    __syncthreads();
    if (tid == 0) out[0] = (fsum[0] + fsum[1] + fsum[2] + fsum[3]) * SCALE;
}

extern "C" void kernel_launch(void* const* d_in, const int* in_sizes, int n_in,
                              void* d_out, int out_size, void* d_ws, size_t ws_size,
                              hipStream_t stream) {
    const float* seg   = (const float*)d_in[0];  // (4,6,8,128,128)
    const float* masks = (const float*)d_in[1];  // (4,6,7,128,128)
    const float* rec   = (const float*)d_in[2];  // (4,6,8,3,128,128)
    const float* rtgt  = (const float*)d_in[3];  // (4,6,3,128,128)
    const float* mvis  = (const float*)d_in[4];  // (4,6,7,128,128)
    const float* ai    = (const float*)d_in[5];  // (4,6,7,8)
    float* out  = (float*)d_out;
    float* part = (float*)d_ws;                  // 1536 floats, fully overwritten each call

    em_loss_kernel<<<NPART, BLOCK, 0, stream>>>(seg, masks, rec, rtgt, mvis, ai, part);
    reduce_kernel<<<1, BLOCK, 0, stream>>>(part, out);
}

// Round 8
// 19.985 us; speedup vs baseline: 5.9577x; 2.2249x over previous
//
#include <hip/hip_runtime.h>

// b=4, f=6, n_slots=7, n_buffer=8, h=w=128, 3 channels. bf=24.
constexpr int NB  = 8;
constexpr int NS  = 7;
constexpr int NCH = 3;
constexpr int HW  = 128 * 128;    // 16384
constexpr int HW2 = HW / 2;       // float2 per plane
constexpr int BF  = 24;
constexpr int BLOCK = 256;
constexpr int PXCHUNKS = HW / (BLOCK * 2);       // 32 px-chunks (512 px each)
constexpr int BLOCKS_PER_BF = PXCHUNKS * 2;      // 64 (x2 c-halves)
constexpr int NPART = BF * BLOCKS_PER_BF;        // 1536 blocks / partials
constexpr float INV_HW = 1.0f / (float)HW;
constexpr float SCALE  = 20.0f / (4.0f * 6.0f * 7.0f * 8.0f);
constexpr float LOG_CLAMP = -100.0f;

__global__ __launch_bounds__(BLOCK, 4)   // VGPR cap 128: room for ~110 live, NO spill
void em_loss_kernel(const float* __restrict__ seg,
                    const float* __restrict__ masks,
                    const float* __restrict__ rec,
                    const float* __restrict__ rtgt,
                    const float* __restrict__ mvis,
                    const float* __restrict__ ai,
                    float* __restrict__ part) {
    const int bid  = blockIdx.x;
    const int bf   = bid >> 6;                   // / BLOCKS_PER_BF
    const int rem  = bid & 63;
    // bit3 = c-half so the two blocks sharing a px-chunk are 8 apart in
    // blockIdx -> same XCD under round-robin dispatch -> L2 dedups shared reads.
    const int half  = (rem >> 3) & 1;
    const int chunk = (rem & 7) | ((rem >> 4) << 3);   // 0..31
    const int tid   = threadIdx.x;
    const int v2    = chunk * BLOCK + tid;       // float2 index in plane
    const int c0    = half * 4;

    __shared__ float ai_s[NS][NB];
    __shared__ float A_s[NB];
    if (tid < NS * NB)
        ((float*)ai_s)[tid] = ai[bf * NS * NB + tid];
    __syncthreads();
    if (tid < NB) {
        float a = 0.f;
        #pragma unroll
        for (int s = 0; s < NS; ++s) a += ai_s[s][tid];
        A_s[tid] = a;
    }
    __syncthreads();

    const float2* segp = (const float2*)(seg  + (size_t)bf * NB * HW)       + v2;
    const float2* mp   = (const float2*)(masks + (size_t)bf * NS * HW)      + v2;
    const float2* rp   = (const float2*)(rec  + (size_t)bf * NB * NCH * HW) + v2;
    const float2* tp   = (const float2*)(rtgt + (size_t)bf * NCH * HW)      + v2;
    const float2* vp   = (const float2*)(mvis + (size_t)bf * NS * HW)       + v2;

    // ---- masks/mvis first; their float2s die into 0/1 bits ----
    float2 mv[NS], vv[NS];
    #pragma unroll
    for (int s = 0; s < NS; ++s) mv[s] = mp[s * HW2];
    #pragma unroll
    for (int s = 0; s < NS; ++s) vv[s] = vp[s * HW2];

    float2 tv[NCH];
    #pragma unroll
    for (int ch = 0; ch < NCH; ++ch) tv[ch] = tp[ch * HW2];

    // seg + rec for this block's 4 buffers
    float2 sv[4];
    #pragma unroll
    for (int c4 = 0; c4 < 4; ++c4) sv[c4] = segp[(c0 + c4) * HW2];

    float2 rr[4][NCH];
    #pragma unroll
    for (int c4 = 0; c4 < 4; ++c4)
        #pragma unroll
        for (int ch = 0; ch < NCH; ++ch)
            rr[c4][ch] = rp[((c0 + c4) * NCH + ch) * HW2];

    // ---- Compute ----
    float mb[NS][2], vb[NS][2];
    #pragma unroll
    for (int s = 0; s < NS; ++s) {
        mb[s][0] = (mv[s].x > 0.5f) ? 1.f : 0.f;
        mb[s][1] = (mv[s].y > 0.5f) ? 1.f : 0.f;
        vb[s][0] = (vv[s].x > 0.5f) ? 1.f : 0.f;
        vb[s][1] = (vv[s].y > 0.5f) ? 1.f : 0.f;
    }

    float acc = 0.f;
    #pragma unroll
    for (int c4 = 0; c4 < 4; ++c4) {
        const int c = c0 + c4;
        const float Ac = A_s[c];
        const float* sp  = (const float*)&sv[c4];
        const float* r0p = (const float*)&rr[c4][0];
        const float* r1p = (const float*)&rr[c4][1];
        const float* r2p = (const float*)&rr[c4][2];
        const float* t0p = (const float*)&tv[0];
        const float* t1p = (const float*)&tv[1];
        const float* t2p = (const float*)&tv[2];
        #pragma unroll
        for (int j = 0; j < 2; ++j) {
            float s  = sp[j];
            float lp = fmaxf(__logf(s), LOG_CLAMP);
            float l1 = fmaxf(__logf(1.0f - s), LOG_CLAMP);
            float d0 = r0p[j] - t0p[j];
            float d1 = r1p[j] - t1p[j];
            float d2 = r2p[j] - t2p[j];
            float D  = d0 * d0 + d1 * d1 + d2 * d2;
            float U = 0.f, V = 0.f;
            #pragma unroll
            for (int s7 = 0; s7 < NS; ++s7) {
                float a = ai_s[s7][c];
                U = fmaf(mb[s7][j], a, U);
                V = fmaf(vb[s7][j], a, V);
            }
            acc += -(Ac * l1 + U * (lp - l1)) * INV_HW + 0.1f * V * D;
        }
    }

    // wave reduce, cross-wave via LDS, one plain store per block (no atomics)
    #pragma unroll
    for (int off = 32; off; off >>= 1) acc += __shfl_down(acc, off, 64);
    __shared__ float wsum[BLOCK / 64];
    const int wid  = tid >> 6;
    const int lane = tid & 63;
    if (lane == 0) wsum[wid] = acc;
    __syncthreads();
    if (tid == 0)
        part[blockIdx.x] = wsum[0] + wsum[1] + wsum[2] + wsum[3];
}

__global__ __launch_bounds__(BLOCK)
void reduce_kernel(const float* __restrict__ part, float* __restrict__ out) {
    const int tid = threadIdx.x;
    float a = 0.f;
    #pragma unroll
    for (int i = 0; i < NPART / BLOCK; ++i)      // 6 each
        a += part[i * BLOCK + tid];
    #pragma unroll
    for (int off = 32; off; off >>= 1) a += __shfl_down(a, off, 64);
    __shared__ float fsum[BLOCK / 64];
    if ((tid & 63) == 0) fsum[tid >> 6] = a;
    __syncthreads();
    if (tid == 0) out[0] = (fsum[0] + fsum[1] + fsum[2] + fsum[3]) * SCALE;
}

extern "C" void kernel_launch(void* const* d_in, const int* in_sizes, int n_in,
                              void* d_out, int out_size, void* d_ws, size_t ws_size,
                              hipStream_t stream) {
    const float* seg   = (const float*)d_in[0];  // (4,6,8,128,128)
    const float* masks = (const float*)d_in[1];  // (4,6,7,128,128)
    const float* rec   = (const float*)d_in[2];  // (4,6,8,3,128,128)
    const float* rtgt  = (const float*)d_in[3];  // (4,6,3,128,128)
    const float* mvis  = (const float*)d_in[4];  // (4,6,7,128,128)
    const float* ai    = (const float*)d_in[5];  // (4,6,7,8)
    float* out  = (float*)d_out;
    float* part = (float*)d_ws;                  // 1536 floats, fully overwritten each call

    em_loss_kernel<<<NPART, BLOCK, 0, stream>>>(seg, masks, rec, rtgt, mvis, ai, part);
    reduce_kernel<<<1, BLOCK, 0, stream>>>(part, out);
}